// Round 13
// baseline (167.563 us; speedup 1.0000x reference)
//
#include <hip/hip_runtime.h>
#include <math.h>

static constexpr int D = 64;
static constexpr int SCAN_BLOCKS = 256;
static constexpr int NB_CHUNK = 96;    // scatter chunk-blocks
static constexpr int GEMM_BLOCKS = 128;
static constexpr int BIN_SHIFT = 6;    // 64 nodes per bin (exact reduce tiles)
static constexpr int MAXBINS = 2048;   // LDS hist/cursor capacity (N <= 131072)

typedef __bf16 bf16x8 __attribute__((ext_vector_type(8)));
typedef float f32x4 __attribute__((ext_vector_type(4)));

// ============================ common helpers ============================

__device__ __forceinline__ unsigned short f2bf(float f) {  // RNE
  unsigned u = __float_as_uint(f);
  return (unsigned short)((u + 0x7fffu + ((u >> 16) & 1u)) >> 16);
}

// Order-preserving bf16 encoding: enc compares as unsigned like the float.
__device__ __forceinline__ unsigned short bf_enc(unsigned short u) {
  const unsigned short s = (unsigned short)(-(int)(u >> 15));  // 0xFFFF if neg
  return (unsigned short)(u ^ (s | 0x8000u));
}
__device__ __forceinline__ float bf_dec_to_f32(unsigned enc32) {
  if (enc32 == 0u) return 0.0f;  // untouched -> 0.0 (fused -inf rule)
  unsigned short enc = (unsigned short)(enc32 >> 16);
  unsigned short u = (enc & 0x8000u) ? (unsigned short)(enc ^ 0x8000u)
                                     : (unsigned short)(~enc);
  return __uint_as_float((unsigned)u << 16);
}

__device__ __forceinline__ void atomic_max_float(float* p, float v, float cur) {
  if (!(v > cur)) return;
  if (v >= 0.0f)
    atomicMax(reinterpret_cast<int*>(p), __float_as_int(v));
  else
    atomicMin(reinterpret_cast<unsigned int*>(p), __float_as_uint(v));
}

__global__ void k_init_neginf(float4* __restrict__ out, int n4) {
  int i = blockIdx.x * blockDim.x + threadIdx.x;
  if (i < n4) {
    float4 v;
    v.x = v.y = v.z = v.w = -INFINITY;
    out[i] = v;
  }
}

// ===================== fat kernel: gemm ∥ lochist =====================
// Blocks [0, NB_CHUNK): per-chunk LDS histogram of dst bins (int4 reads).
// Blocks [NB_CHUNK, NB_CHUNK+GEMM_BLOCKS): MFMA precompute
//   yb[t][n][o] = ENC16(bf16(b[t][o] + sum_k x[n][k]*W[t][k][o])).
__global__ __launch_bounds__(1024) void k_gemm_hist(
    const float* __restrict__ x, const float* __restrict__ W,
    const float* __restrict__ b, unsigned short* __restrict__ yb,
    const int* __restrict__ dst, int* __restrict__ countsT,
    int nN, int nE, int nBins, int chunk) {
  __shared__ int lh[MAXBINS];
  const int t = threadIdx.x;

  if (blockIdx.x < NB_CHUNK) {
    // ---------------- histogram part ----------------
    for (int i = t; i < nBins; i += 1024) lh[i] = 0;
    __syncthreads();
    const int beg = blockIdx.x * chunk;
    const int end = min(beg + chunk, nE);
    int i = beg + t * 4;
    for (; i + 3 < end; i += 4096) {
      const int4 d4 = *reinterpret_cast<const int4*>(dst + i);
      atomicAdd(&lh[d4.x >> BIN_SHIFT], 1);
      atomicAdd(&lh[d4.y >> BIN_SHIFT], 1);
      atomicAdd(&lh[d4.z >> BIN_SHIFT], 1);
      atomicAdd(&lh[d4.w >> BIN_SHIFT], 1);
    }
    for (; i < end; ++i) atomicAdd(&lh[dst[i] >> BIN_SHIFT], 1);
    __syncthreads();
    for (int i2 = t; i2 < nBins; i2 += 1024)
      countsT[(size_t)i2 * NB_CHUNK + blockIdx.x] = lh[i2];
    return;
  }

  // ---------------- gemm part ----------------
  const int lane = t & 63;
  const int wid = (blockIdx.x - NB_CHUNK) * 16 + (t >> 6);
  const int nWaves = GEMM_BLOCKS * 16;
  const int kgrp = (lane >> 4) << 3;  // 0,8,16,24
  const int nsub = lane & 15;

  bf16x8 Bf[8][2];
  float bias[8];
#pragma unroll
  for (int nt = 0; nt < 8; ++nt) {
    const int ty = nt >> 2;
    const int n = ((nt & 3) << 4) + nsub;
#pragma unroll
    for (int ks = 0; ks < 2; ++ks) {
      bf16x8 f;
#pragma unroll
      for (int e = 0; e < 8; ++e) {
        const int k = (ks << 5) + kgrp + e;
        f[e] = (__bf16)W[ty * 4096 + k * 64 + n];
      }
      Bf[nt][ks] = f;
    }
    bias[nt] = b[ty * 64 + n];
  }

  const int nChunks = (nN + 15) >> 4;
  for (int c = wid; c < nChunks; c += nWaves) {
    const int base = c << 4;
    const int arow = min(base + nsub, nN - 1);
    const float4 xa0 = *reinterpret_cast<const float4*>(x + (size_t)arow * 64 + kgrp);
    const float4 xa1 = *reinterpret_cast<const float4*>(x + (size_t)arow * 64 + kgrp + 4);
    const float4 xb0 = *reinterpret_cast<const float4*>(x + (size_t)arow * 64 + 32 + kgrp);
    const float4 xb1 = *reinterpret_cast<const float4*>(x + (size_t)arow * 64 + 36 + kgrp);
    bf16x8 a0, a1;
    a0[0] = (__bf16)xa0.x; a0[1] = (__bf16)xa0.y; a0[2] = (__bf16)xa0.z; a0[3] = (__bf16)xa0.w;
    a0[4] = (__bf16)xa1.x; a0[5] = (__bf16)xa1.y; a0[6] = (__bf16)xa1.z; a0[7] = (__bf16)xa1.w;
    a1[0] = (__bf16)xb0.x; a1[1] = (__bf16)xb0.y; a1[2] = (__bf16)xb0.z; a1[3] = (__bf16)xb0.w;
    a1[4] = (__bf16)xb1.x; a1[5] = (__bf16)xb1.y; a1[6] = (__bf16)xb1.z; a1[7] = (__bf16)xb1.w;
#pragma unroll
    for (int nt = 0; nt < 8; ++nt) {
      f32x4 acc = {bias[nt], bias[nt], bias[nt], bias[nt]};
      acc = __builtin_amdgcn_mfma_f32_16x16x32_bf16(a0, Bf[nt][0], acc, 0, 0, 0);
      acc = __builtin_amdgcn_mfma_f32_16x16x32_bf16(a1, Bf[nt][1], acc, 0, 0, 0);
      const int ty = nt >> 2;
      const int o = ((nt & 3) << 4) + nsub;
      const int rbase = base + ((lane >> 4) << 2);
#pragma unroll
      for (int r = 0; r < 4; ++r) {
        const int node = rbase + r;
        if (node < nN)
          yb[((size_t)ty * nN + node) * 64 + o] = bf_enc(f2bf(acc[r]));
      }
    }
  }
}

// Phase 2a: per-segment sums -> blockSums[SCAN_BLOCKS].
__global__ __launch_bounds__(256) void k_scan_partial(
    const int* __restrict__ counts, int* __restrict__ blockSums, int nN) {
  __shared__ int red[256];
  const int t = threadIdx.x;
  const int seg = (nN + gridDim.x - 1) / gridDim.x;
  const int beg = blockIdx.x * seg;
  const int end = min(beg + seg, nN);
  int s = 0;
  for (int i = beg + t; i < end; i += 256) s += counts[i];
  red[t] = s;
  __syncthreads();
  for (int d = 128; d > 0; d >>= 1) {
    if (t < d) red[t] += red[t + d];
    __syncthreads();
  }
  if (t == 0) blockSums[blockIdx.x] = red[0];
}

// Phase 2b: write exclusive offsets; each block locally scans blockSums.
__global__ __launch_bounds__(256) void k_scan_write(
    const int* __restrict__ counts, const int* __restrict__ blockSums,
    int* __restrict__ offs, int nN) {
  __shared__ int bs[256];
  __shared__ int sh[256];
  const int t = threadIdx.x;
  bs[t] = blockSums[t];
  __syncthreads();
  for (int d = 1; d < 256; d <<= 1) {
    const int o = (t >= d) ? bs[t - d] : 0;
    __syncthreads();
    bs[t] += o;
    __syncthreads();
  }
  const int bid = blockIdx.x;
  int carry = (bid > 0) ? bs[bid - 1] : 0;
  const int total = bs[255];
  const int seg = (nN + gridDim.x - 1) / gridDim.x;
  const int beg = bid * seg;
  const int end = min(beg + seg, nN);
  for (int base = beg; base < end; base += 256) {
    const int i = base + t;
    const int v = (i < end) ? counts[i] : 0;
    sh[t] = v;
    __syncthreads();
    for (int d = 1; d < 256; d <<= 1) {
      const int o = (t >= d) ? sh[t - d] : 0;
      __syncthreads();
      sh[t] += o;
      __syncthreads();
    }
    if (i < end) offs[i] = carry + sh[t] - v;
    carry += sh[255];
    __syncthreads();
  }
  if (bid == gridDim.x - 1 && t == 0) offs[nN] = total;
}

// Phase 3: scatter records; LDS cursor atomics only; int4 edge reads.
// Record: row = type*nN + src in bits 0-20 | dstLow in bits 21-26.
__global__ __launch_bounds__(1024) void k_cscatter(
    const int* __restrict__ src, const int* __restrict__ dst,
    const int* __restrict__ ea, const int* __restrict__ offs,
    unsigned* __restrict__ rec, int nN, int nE, int nBins, int chunk) {
  __shared__ int cur[MAXBINS];
  const int t = threadIdx.x;
  for (int i = t; i < nBins; i += 1024)
    cur[i] = offs[(size_t)i * NB_CHUNK + blockIdx.x];
  __syncthreads();
  const int beg = blockIdx.x * chunk;
  const int end = min(beg + chunk, nE);
  int i = beg + t * 4;
  for (; i + 3 < end; i += 4096) {
    const int4 s4 = *reinterpret_cast<const int4*>(src + i);
    const int4 d4 = *reinterpret_cast<const int4*>(dst + i);
    const int4 e4 = *reinterpret_cast<const int4*>(ea + i);
    {
      const int pos = atomicAdd(&cur[d4.x >> BIN_SHIFT], 1);
      rec[pos] = (unsigned)(s4.x + e4.x * nN) |
                 ((unsigned)(d4.x & ((1 << BIN_SHIFT) - 1)) << 21);
    }
    {
      const int pos = atomicAdd(&cur[d4.y >> BIN_SHIFT], 1);
      rec[pos] = (unsigned)(s4.y + e4.y * nN) |
                 ((unsigned)(d4.y & ((1 << BIN_SHIFT) - 1)) << 21);
    }
    {
      const int pos = atomicAdd(&cur[d4.z >> BIN_SHIFT], 1);
      rec[pos] = (unsigned)(s4.z + e4.z * nN) |
                 ((unsigned)(d4.z & ((1 << BIN_SHIFT) - 1)) << 21);
    }
    {
      const int pos = atomicAdd(&cur[d4.w >> BIN_SHIFT], 1);
      rec[pos] = (unsigned)(s4.w + e4.w * nN) |
                 ((unsigned)(d4.w & ((1 << BIN_SHIFT) - 1)) << 21);
    }
  }
  for (; i < end; ++i) {
    const int d = dst[i];
    const int pos = atomicAdd(&cur[d >> BIN_SHIFT], 1);
    rec[pos] = (unsigned)(src[i] + ea[i] * nN) |
               ((unsigned)(d & ((1 << BIN_SHIFT) - 1)) << 21);
  }
}

// ============================ reduction ============================
// One block per 64-node bin, EXACT record range, 8 waves split it.
// Records are wave-uniform -> readfirstlane scalarizes row/dst fields:
// load = saddr + lane offset, ~3 VALU/record. acc init 0 = untouched.
__global__ __launch_bounds__(512) void k_reduce_bin(
    const int* __restrict__ offs, const unsigned* __restrict__ rec,
    const unsigned short* __restrict__ yb, float* __restrict__ out, int nN) {
  __shared__ unsigned acc[64 * 64];  // 16 KB
  const int t = threadIdx.x;
#pragma unroll
  for (int i = 0; i < 8; ++i) acc[t + i * 512] = 0u;
  __syncthreads();

  const int bin = blockIdx.x;
  const int beg = offs[bin * NB_CHUNK];
  const int cnt = offs[(bin + 1) * NB_CHUNK] - beg;
  const int w = t >> 6;
  const unsigned lane = t & 63;
  const int myBeg = beg + ((cnt * w) >> 3);
  const int myEnd = beg + ((cnt * (w + 1)) >> 3);

  int j = myBeg;
  for (; j + 7 < myEnd; j += 8) {
    unsigned r[8];
#pragma unroll
    for (int q = 0; q < 8; ++q)
      r[q] = __builtin_amdgcn_readfirstlane(rec[j + q]);
    unsigned v[8];
#pragma unroll
    for (int q = 0; q < 8; ++q)
      v[q] = (unsigned)yb[((r[q] & 0x1FFFFFu) << 6) + lane] << 16;
#pragma unroll
    for (int q = 0; q < 8; ++q)
      atomicMax(&acc[((r[q] >> 21) << 6) + lane], v[q]);
  }
  for (; j < myEnd; ++j) {
    const unsigned r0 = __builtin_amdgcn_readfirstlane(rec[j]);
    const unsigned v0 = (unsigned)yb[((r0 & 0x1FFFFFu) << 6) + lane] << 16;
    atomicMax(&acc[((r0 >> 21) << 6) + lane], v0);
  }
  __syncthreads();

  const int nodeBase = bin << 6;
  for (int f = t; f < 64 * 16; f += 512) {  // one float4 per f
    const int node = nodeBase + (f >> 4);
    if (node < nN) {
      float4 v;
      v.x = bf_dec_to_f32(acc[f * 4 + 0]);
      v.y = bf_dec_to_f32(acc[f * 4 + 1]);
      v.z = bf_dec_to_f32(acc[f * 4 + 2]);
      v.w = bf_dec_to_f32(acc[f * 4 + 3]);
      *reinterpret_cast<float4*>(&out[(size_t)node * 64 + (f & 15) * 4]) = v;
    }
  }
}

// ============================ fallback kernels ============================

__global__ void k_fixup(float4* __restrict__ out, int n4) {
  int i = blockIdx.x * blockDim.x + threadIdx.x;
  if (i < n4) {
    float4 v = out[i];
    if (v.x == -INFINITY) v.x = 0.0f;
    if (v.y == -INFINITY) v.y = 0.0f;
    if (v.z == -INFINITY) v.z = 0.0f;
    if (v.w == -INFINITY) v.w = 0.0f;
    out[i] = v;
  }
}

__global__ __launch_bounds__(256) void k_edge_direct(
    const float* __restrict__ x, const float* __restrict__ W,
    const float* __restrict__ b, const int* __restrict__ ei,
    const int* __restrict__ ea, float* __restrict__ out, int nEdges) {
  __shared__ float Wl[2 * D * D];
  __shared__ float bl[2 * D];
  for (int i = threadIdx.x; i < 2 * D * D; i += 256) Wl[i] = W[i];
  for (int i = threadIdx.x; i < 2 * D; i += 256) bl[i] = b[i];
  __syncthreads();
  const int wave = threadIdx.x >> 6;
  const int lane = threadIdx.x & 63;
  for (int e = blockIdx.x * 4 + wave; e < nEdges; e += gridDim.x * 4) {
    const int src = ei[e];
    const int dst = ei[nEdges + e];
    const int t = ea[e];
    const float xk = x[(size_t)src * D + lane];
    float acc = bl[t * D + lane];
    const float* Wt = &Wl[t * D * D];
#pragma unroll
    for (int k = 0; k < D; ++k)
      acc = fmaf(__shfl(xk, k, 64), Wt[k * D + lane], acc);
    float* p = out + (size_t)dst * D + lane;
    const float cur = *p;
    atomic_max_float(p, acc, cur);
  }
}

// ============================ launcher ============================

extern "C" void kernel_launch(void* const* d_in, const int* in_sizes, int n_in,
                              void* d_out, int out_size, void* d_ws, size_t ws_size,
                              hipStream_t stream) {
  const float* x = (const float*)d_in[0];
  const float* W = (const float*)d_in[1];
  const float* b = (const float*)d_in[2];
  const int* ei = (const int*)d_in[3];   // [2, E]: src row then dst row
  const int* ea = (const int*)d_in[4];   // [E]
  float* out = (float*)d_out;

  const int nNodes = in_sizes[0] / D;
  const int nEdges = in_sizes[4];
  const int n4out = (nNodes * D) / 4;
  const int nBins = (nNodes + (1 << BIN_SHIFT) - 1) >> BIN_SHIFT;
  const int nScan = nBins * NB_CHUNK;
  const int chunk = (nEdges + NB_CHUNK - 1) / NB_CHUNK;

  // Workspace carve (256B-aligned regions).
  auto rup = [](size_t v) { return (v + 255) & ~(size_t)255; };
  const size_t ybB = (size_t)2 * nNodes * D * sizeof(unsigned short);
  const size_t offYb = 0;
  const size_t offCT = rup(offYb + ybB);
  const size_t offOffs = rup(offCT + (size_t)nScan * sizeof(int));
  const size_t offBS = rup(offOffs + (size_t)(nScan + 1) * sizeof(int));
  const size_t offRec = rup(offBS + (size_t)SCAN_BLOCKS * sizeof(int));
  const size_t need = offRec + (size_t)nEdges * sizeof(unsigned);

  if (ws_size >= need && nNodes < (1 << 20) && nBins <= MAXBINS) {
    // ---- bf16 MFMA + deterministic two-level scatter path ----
    char* ws = (char*)d_ws;
    unsigned short* yb = (unsigned short*)(ws + offYb);
    int* countsT = (int*)(ws + offCT);
    int* offs = (int*)(ws + offOffs);
    int* blockSums = (int*)(ws + offBS);
    unsigned* rec = (unsigned*)(ws + offRec);

    const int* srcRow = ei;
    const int* dstRow = ei + nEdges;

    k_gemm_hist<<<NB_CHUNK + GEMM_BLOCKS, 1024, 0, stream>>>(
        x, W, b, yb, dstRow, countsT, nNodes, nEdges, nBins, chunk);
    k_scan_partial<<<SCAN_BLOCKS, 256, 0, stream>>>(countsT, blockSums, nScan);
    k_scan_write<<<SCAN_BLOCKS, 256, 0, stream>>>(countsT, blockSums, offs, nScan);
    k_cscatter<<<NB_CHUNK, 1024, 0, stream>>>(srcRow, dstRow, ea, offs, rec,
                                              nNodes, nEdges, nBins, chunk);
    k_reduce_bin<<<nBins, 512, 0, stream>>>(offs, rec, yb, out, nNodes);
  } else {
    // ---- fallback: direct edge compute with filtered atomics ----
    k_init_neginf<<<(n4out + 255) / 256, 256, 0, stream>>>((float4*)out, n4out);
    k_edge_direct<<<4096, 256, 0, stream>>>(x, W, b, ei, ea, out, nEdges);
    k_fixup<<<(n4out + 255) / 256, 256, 0, stream>>>((float4*)out, n4out);
  }
}